// Round 6
// baseline (1276.797 us; speedup 1.0000x reference)
//
#include <hip/hip_runtime.h>
#include <hip/hip_bf16.h>
#include <math.h>

// ---------------------------------------------------------------------------
// MambaBlock (bimamba v2). Round 5:
//  - dt_proj rewritten as specialized K=48 fully-unrolled kernel (64x128 tile,
//    no k-loop barriers, conflict-free LDS layouts, 768 blocks) replacing the
//    generic gemm_tn (56us, 737K bank conflicts, 13% occupancy)
//  - everything else unchanged from R4.
// Shapes: B=4, L=1024, D_MODEL=768, D_INNER=1536, DT_RANK=48, D_STATE=16.
// ---------------------------------------------------------------------------

#define BB 4
#define LL 1024
#define DM 768
#define DI 1536
#define RK 48
#define NS 16
#define CH 32          // scan chunks
#define CLEN 32        // LL / CH
#define DB6 (DI / 256) // d-blocks per batch in scan
#define XKS 8          // x_proj split-K chunks
#define XKC 192        // 1536 / XKS

typedef __attribute__((ext_vector_type(8))) short bf16x8;
typedef __attribute__((ext_vector_type(4))) float f32x4;

__device__ __forceinline__ float siluf(float x) {
    return x / (1.f + __expf(-x));
}
__device__ __forceinline__ float softplusf(float x) {
    return (x > 20.f) ? x : log1pf(__expf(x));
}
__device__ __forceinline__ unsigned short f2bf(float x) {
    __hip_bfloat16 h = __float2bfloat16(x);
    return *(unsigned short*)&h;
}
__device__ __forceinline__ void async_cp16(const void* g, void* l) {
    __builtin_amdgcn_global_load_lds(
        (const __attribute__((address_space(1))) void*)g,
        (__attribute__((address_space(3))) void*)l, 16, 0, 0);
}

// ---------------- LayerNorm: one block per row of 768, bf16 out ------------
__global__ __launch_bounds__(256)
void ln_kernel(const float* __restrict__ h, const float* __restrict__ w,
               const float* __restrict__ bvec, unsigned short* __restrict__ out)
{
    int row = blockIdx.x;                 // 0 .. B*L-1
    const float* x = h + (size_t)row * DM;
    int tid = threadIdx.x;
    float v[3];
    float s = 0.f, s2 = 0.f;
#pragma unroll
    for (int j = 0; j < 3; ++j) {
        v[j] = x[tid + j * 256];
        s += v[j];
        s2 += v[j] * v[j];
    }
#pragma unroll
    for (int off = 32; off > 0; off >>= 1) {
        s += __shfl_down(s, off);
        s2 += __shfl_down(s2, off);
    }
    __shared__ float sw[4], sw2[4], stat[2];
    int wid = tid >> 6;
    if ((tid & 63) == 0) { sw[wid] = s; sw2[wid] = s2; }
    __syncthreads();
    if (tid == 0) {
        float a = sw[0] + sw[1] + sw[2] + sw[3];
        float a2 = sw2[0] + sw2[1] + sw2[2] + sw2[3];
        float mu = a * (1.f / DM);
        float var = a2 * (1.f / DM) - mu * mu;
        stat[0] = mu;
        stat[1] = rsqrtf(var + 1e-5f);
    }
    __syncthreads();
    float mu = stat[0], rs = stat[1];
    unsigned short* o = out + (size_t)row * DM;
#pragma unroll
    for (int j = 0; j < 3; ++j) {
        int i = tid + j * 256;
        o[i] = f2bf((v[j] - mu) * rs * w[i] + bvec[i]);
    }
}

// ---------------- fp32 -> bf16 cast (4 elems / thread) ---------------------
__global__ __launch_bounds__(256)
void cast_kernel(const float* __restrict__ x, unsigned short* __restrict__ y)
{
    int i = (blockIdx.x * 256 + threadIdx.x) * 4;
    float4 v = *(const float4*)(x + i);
    y[i + 0] = f2bf(v.x);
    y[i + 1] = f2bf(v.y);
    y[i + 2] = f2bf(v.z);
    y[i + 3] = f2bf(v.w);
}

// ---------------- Avm = -exp(A_log) ----------------------------------------
__global__ __launch_bounds__(256)
void aexp_kernel(const float* __restrict__ A_log, float* __restrict__ Avm)
{
    int i = blockIdx.x * 256 + threadIdx.x;     // over DI*NS
    Avm[i] = -expf(A_log[i]);
}

// ---------------- bf16 MFMA GEMM: C = A @ B^T (fp32 out) -------------------
// async global->LDS staging (16B/lane), 128x128 tile, BK=32.
__global__ __launch_bounds__(256)
void gemm_mfma_bt(const unsigned short* __restrict__ A, int lda,
                  const unsigned short* __restrict__ B, int ldb,
                  float* __restrict__ C, int ldc, int K)
{
    __shared__ unsigned short As[128 * 32];
    __shared__ unsigned short Bs[128 * 32];
    int tid = threadIdx.x;
    int wave = tid >> 6, lane = tid & 63;
    int wm = wave & 1, wn = wave >> 1;      // 2x2 wave grid
    int quad = lane >> 4, lr = lane & 15;
    int m0 = blockIdx.y * 128, n0 = blockIdx.x * 128;

    f32x4 acc[4][4];
#pragma unroll
    for (int i = 0; i < 4; ++i)
#pragma unroll
        for (int j = 0; j < 4; ++j) acc[i][j] = (f32x4){0.f, 0.f, 0.f, 0.f};

    for (int kt = 0; kt < K; kt += 32) {
        // stage 128x32 of A and B: LDS dest = wave-uniform base + lane*16
#pragma unroll
        for (int i = 0; i < 2; ++i) {
            int idx = tid + i * 256;               // 0..511
            int row = idx >> 2, col = (idx & 3) * 8;
            async_cp16(A + (size_t)(m0 + row) * lda + kt + col, &As[idx * 8]);
            async_cp16(B + (size_t)(n0 + row) * ldb + kt + col, &Bs[idx * 8]);
        }
        __syncthreads();

        bf16x8 af[4], bf[4];
#pragma unroll
        for (int mt = 0; mt < 4; ++mt)
            af[mt] = *(const bf16x8*)(&As[(wm * 64 + mt * 16 + lr) * 32 + quad * 8]);
#pragma unroll
        for (int nt = 0; nt < 4; ++nt)
            bf[nt] = *(const bf16x8*)(&Bs[(wn * 64 + nt * 16 + lr) * 32 + quad * 8]);
#pragma unroll
        for (int mt = 0; mt < 4; ++mt)
#pragma unroll
            for (int nt = 0; nt < 4; ++nt)
                acc[mt][nt] = __builtin_amdgcn_mfma_f32_16x16x32_bf16(
                    af[mt], bf[nt], acc[mt][nt], 0, 0, 0);
        __syncthreads();
    }

#pragma unroll
    for (int mt = 0; mt < 4; ++mt) {
#pragma unroll
        for (int nt = 0; nt < 4; ++nt) {
#pragma unroll
            for (int e = 0; e < 4; ++e) {
                int m = m0 + wm * 64 + mt * 16 + quad * 4 + e;
                int n = n0 + wn * 64 + nt * 16 + lr;
                C[(size_t)m * ldc + n] = acc[mt][nt][e];
            }
        }
    }
}

// ---------------- dt_proj: C = softplus(A[:, :48] @ W^T + bias) -------------
// A: xdbl [4096 x 80] (use first 48 cols); W: [1536 x 48]; C: [4096 x 1536].
// 64x128 tile, K=48 fully unrolled, single stage, no k-loop barriers.
__global__ __launch_bounds__(256)
void dtproj_kernel(const float* __restrict__ A, const float* __restrict__ W,
                   const float* __restrict__ bias, float* __restrict__ C)
{
    __shared__ float As[64][48];    // [m][k]; reads are 2-addr broadcast
    __shared__ float Ws[48][128];   // [k][n]; float4 reads, conflict-free
    int tid = threadIdx.x;
    int m0 = blockIdx.y * 64, n0 = blockIdx.x * 128;

    // stage A: 64 rows x 48 cols = 768 float4
    for (int i = tid; i < 768; i += 256) {
        int r = i / 12, j = i % 12;
        *(float4*)(&As[r][j * 4]) =
            *(const float4*)(A + (size_t)(m0 + r) * 80 + j * 4);
    }
    // stage W transposed: 128 rows x 48 cols = 1536 float4
    for (int i = tid; i < 1536; i += 256) {
        int r = i / 12, j = i % 12;
        float4 v = *(const float4*)(W + (size_t)(n0 + r) * RK + j * 4);
        Ws[j * 4 + 0][r] = v.x;
        Ws[j * 4 + 1][r] = v.y;
        Ws[j * 4 + 2][r] = v.z;
        Ws[j * 4 + 3][r] = v.w;
    }
    __syncthreads();

    int tx = tid & 31, ty = tid >> 5;   // tx: 4-col group, ty: 8-row group
    float acc[8][4];
#pragma unroll
    for (int i = 0; i < 8; ++i)
#pragma unroll
        for (int j = 0; j < 4; ++j) acc[i][j] = 0.f;

#pragma unroll
    for (int k = 0; k < RK; ++k) {
        float4 w = *(const float4*)(&Ws[k][tx * 4]);
        float a[8];
#pragma unroll
        for (int i = 0; i < 8; ++i) a[i] = As[ty * 8 + i][k];
#pragma unroll
        for (int i = 0; i < 8; ++i) {
            acc[i][0] += a[i] * w.x;
            acc[i][1] += a[i] * w.y;
            acc[i][2] += a[i] * w.z;
            acc[i][3] += a[i] * w.w;
        }
    }

    float4 bv = *(const float4*)(bias + n0 + tx * 4);
#pragma unroll
    for (int i = 0; i < 8; ++i) {
        float4 o;
        o.x = softplusf(acc[i][0] + bv.x);
        o.y = softplusf(acc[i][1] + bv.y);
        o.z = softplusf(acc[i][2] + bv.z);
        o.w = softplusf(acc[i][3] + bv.w);
        *(float4*)(C + (size_t)(m0 + ty * 8 + i) * DI + n0 + tx * 4) = o;
    }
}

// ---------------- x_proj split-K partial GEMM -------------------------------
__global__ __launch_bounds__(256)
void xproj_partial(const float* __restrict__ A, const float* __restrict__ W,
                   float* __restrict__ part)
{
    __shared__ float As[32][68];
    __shared__ float Ws[32][84];
    int tid = threadIdx.x;
    int tx = tid & 15, ty = tid >> 4;
    int k0 = blockIdx.x * XKC;
    int m0 = blockIdx.y * 64;

    float acc[4][5];
#pragma unroll
    for (int i = 0; i < 4; ++i)
#pragma unroll
        for (int j = 0; j < 5; ++j) acc[i][j] = 0.f;

    for (int kt = 0; kt < XKC; kt += 32) {
#pragma unroll
        for (int i = 0; i < 2; ++i) {
            int idx = tid + i * 256;
            int r = idx >> 3, c4 = (idx & 7) * 4;
            float4 v = *(const float4*)(A + (size_t)(m0 + r) * DI + k0 + kt + c4);
            As[c4 + 0][r] = v.x;
            As[c4 + 1][r] = v.y;
            As[c4 + 2][r] = v.z;
            As[c4 + 3][r] = v.w;
        }
        for (int idx = tid; idx < 640; idx += 256) {
            int r = idx >> 3, c4 = (idx & 7) * 4;
            float4 v = *(const float4*)(W + (size_t)r * DI + k0 + kt + c4);
            Ws[c4 + 0][r] = v.x;
            Ws[c4 + 1][r] = v.y;
            Ws[c4 + 2][r] = v.z;
            Ws[c4 + 3][r] = v.w;
        }
        __syncthreads();
#pragma unroll
        for (int kk = 0; kk < 32; ++kk) {
            float a[4], w[5];
#pragma unroll
            for (int i = 0; i < 4; ++i) a[i] = As[kk][ty * 4 + i];
#pragma unroll
            for (int j = 0; j < 5; ++j) w[j] = Ws[kk][tx + 16 * j];
#pragma unroll
            for (int i = 0; i < 4; ++i)
#pragma unroll
                for (int j = 0; j < 5; ++j) acc[i][j] += a[i] * w[j];
        }
        __syncthreads();
    }

    float* p = part + ((size_t)blockIdx.x * BB * LL + m0) * 80;
#pragma unroll
    for (int i = 0; i < 4; ++i)
#pragma unroll
        for (int j = 0; j < 5; ++j)
            p[(size_t)(ty * 4 + i) * 80 + tx + 16 * j] = acc[i][j];
}

// ---------------- x_proj reduce: xdbl = sum over XKS partials ---------------
__global__ __launch_bounds__(256)
void xproj_reduce(const float* __restrict__ part, float* __restrict__ xdbl)
{
    int i = blockIdx.x * 256 + threadIdx.x;     // over 4096*80
    float s = 0.f;
#pragma unroll
    for (int ks = 0; ks < XKS; ++ks)
        s += part[(size_t)ks * BB * LL * 80 + i];
    xdbl[i] = s;
}

// ---------------- causal depthwise conv (k=4) + silu ------------------------
__global__ __launch_bounds__(256)
void conv_silu_kernel(const float* __restrict__ xz, const float* __restrict__ w,
                      const float* __restrict__ bias, float* __restrict__ xc,
                      int rev)
{
    int gid = blockIdx.x * 256 + threadIdx.x;   // over B*L*DI
    int d = gid % DI;
    int bt = gid / DI;
    int t = bt % LL;
    int b = bt / LL;
    float acc = bias[d];
#pragma unroll
    for (int i = 0; i < 4; ++i) {
        int tt = t - 3 + i;
        if (tt >= 0) {
            int st = rev ? (LL - 1 - tt) : tt;
            acc += xz[((size_t)(b * LL + st)) * (2 * DI) + d] * w[d * 4 + i];
        }
    }
    xc[gid] = siluf(acc);
}

// ---------------- selective scan, pass 1: per-chunk (p, q) ------------------
__global__ __launch_bounds__(256)
void scan_p1(const float* __restrict__ dt, const float* __restrict__ u,
             const float* __restrict__ xdbl, const float* __restrict__ Avm,
             float2* __restrict__ PQ)
{
    int c = blockIdx.y;
    int b = blockIdx.x / DB6;
    int d = (blockIdx.x % DB6) * 256 + threadIdx.x;

    float Av[16];
    {
        const float4* a4 = (const float4*)(Avm + (size_t)d * NS);
#pragma unroll
        for (int j = 0; j < 4; ++j) {
            float4 v = a4[j];
            Av[4 * j + 0] = v.x; Av[4 * j + 1] = v.y;
            Av[4 * j + 2] = v.z; Av[4 * j + 3] = v.w;
        }
    }

    __shared__ float Bs[CLEN * NS];
    for (int i = threadIdx.x; i < CLEN * NS; i += 256) {
        int t = i >> 4, n = i & 15;
        Bs[i] = xdbl[((size_t)(b * LL + c * CLEN + t)) * 80 + 48 + n];
    }
    __syncthreads();

    float q[16];
#pragma unroll
    for (int n = 0; n < 16; ++n) q[n] = 0.f;
    float dtsum = 0.f;

    size_t base = ((size_t)b * LL + c * CLEN) * DI + d;
    float dtr[8], ur[8];
#pragma unroll
    for (int i = 0; i < 8; ++i) {
        dtr[i] = dt[base + (size_t)i * DI];
        ur[i]  = u[base + (size_t)i * DI];
    }
#pragma unroll
    for (int t = 0; t < CLEN; ++t) {
        float dtv = dtr[t & 7], uv = ur[t & 7];
        if (t + 8 < CLEN) {
            dtr[t & 7] = dt[base + (size_t)(t + 8) * DI];
            ur[t & 7]  = u[base + (size_t)(t + 8) * DI];
        }
        float du = dtv * uv;
        dtsum += dtv;
        const float4* b4 = (const float4*)(Bs + t * NS);
#pragma unroll
        for (int j = 0; j < 4; ++j) {
            float4 Bv = b4[j];
            q[4 * j + 0] = __expf(dtv * Av[4 * j + 0]) * q[4 * j + 0] + du * Bv.x;
            q[4 * j + 1] = __expf(dtv * Av[4 * j + 1]) * q[4 * j + 1] + du * Bv.y;
            q[4 * j + 2] = __expf(dtv * Av[4 * j + 2]) * q[4 * j + 2] + du * Bv.z;
            q[4 * j + 3] = __expf(dtv * Av[4 * j + 3]) * q[4 * j + 3] + du * Bv.w;
        }
    }

    float2* o = PQ + (size_t)c * (BB * DI * NS) + (size_t)(b * DI + d) * NS;
#pragma unroll
    for (int n = 0; n < 16; ++n)
        o[n] = make_float2(__expf(dtsum * Av[n]), q[n]);
}

// ---------------- scan mid: compose chunk prefixes -> H0 --------------------
__global__ __launch_bounds__(256)
void scan_mid(const float2* __restrict__ PQ, float* __restrict__ H0)
{
    int gid = blockIdx.x * 256 + threadIdx.x;   // over BB*DI*NS
    float h = 0.f;
#pragma unroll
    for (int c = 0; c < CH; ++c) {
        H0[(size_t)c * (BB * DI * NS) + gid] = h;
        float2 s = PQ[(size_t)c * (BB * DI * NS) + gid];
        h = s.x * h + s.y;
    }
}

// ---------------- selective scan, pass 2: replay with true h0 ---------------
__global__ __launch_bounds__(256)
void scan_p2(const float* __restrict__ dt, const float* __restrict__ u,
             const float* __restrict__ xdbl, const float* __restrict__ Avm,
             const float* __restrict__ Dp, const float* __restrict__ H0,
             float* __restrict__ g, int rev)
{
    int c = blockIdx.y;
    int b = blockIdx.x / DB6;
    int d = (blockIdx.x % DB6) * 256 + threadIdx.x;

    float Av[16];
    {
        const float4* a4 = (const float4*)(Avm + (size_t)d * NS);
#pragma unroll
        for (int j = 0; j < 4; ++j) {
            float4 v = a4[j];
            Av[4 * j + 0] = v.x; Av[4 * j + 1] = v.y;
            Av[4 * j + 2] = v.z; Av[4 * j + 3] = v.w;
        }
    }
    float h[16];
    {
        const float4* h4 = (const float4*)(H0 + (size_t)c * (BB * DI * NS)
                                           + (size_t)(b * DI + d) * NS);
#pragma unroll
        for (int j = 0; j < 4; ++j) {
            float4 v = h4[j];
            h[4 * j + 0] = v.x; h[4 * j + 1] = v.y;
            h[4 * j + 2] = v.z; h[4 * j + 3] = v.w;
        }
    }
    float Dpv = Dp[d];

    __shared__ float Bs[CLEN * NS];
    __shared__ float Cs[CLEN * NS];
    for (int i = threadIdx.x; i < CLEN * NS; i += 256) {
        int t = i >> 4, n = i & 15;
        size_t src = ((size_t)(b * LL + c * CLEN + t)) * 80;
        Bs[i] = xdbl[src + 48 + n];
        Cs[i] = xdbl[src + 64 + n];
    }
    __syncthreads();

    size_t base = ((size_t)b * LL + c * CLEN) * DI + d;
    float dtr[8], ur[8];
#pragma unroll
    for (int i = 0; i < 8; ++i) {
        dtr[i] = dt[base + (size_t)i * DI];
        ur[i]  = u[base + (size_t)i * DI];
    }
#pragma unroll
    for (int t = 0; t < CLEN; ++t) {
        float dtv = dtr[t & 7], uv = ur[t & 7];
        if (t + 8 < CLEN) {
            dtr[t & 7] = dt[base + (size_t)(t + 8) * DI];
            ur[t & 7]  = u[base + (size_t)(t + 8) * DI];
        }
        float du = dtv * uv;
        float y = 0.f;
        const float4* b4 = (const float4*)(Bs + t * NS);
        const float4* c4 = (const float4*)(Cs + t * NS);
#pragma unroll
        for (int j = 0; j < 4; ++j) {
            float4 Bv = b4[j];
            float4 Cv = c4[j];
            h[4 * j + 0] = __expf(dtv * Av[4 * j + 0]) * h[4 * j + 0] + du * Bv.x;
            h[4 * j + 1] = __expf(dtv * Av[4 * j + 1]) * h[4 * j + 1] + du * Bv.y;
            h[4 * j + 2] = __expf(dtv * Av[4 * j + 2]) * h[4 * j + 2] + du * Bv.z;
            h[4 * j + 3] = __expf(dtv * Av[4 * j + 3]) * h[4 * j + 3] + du * Bv.w;
            y += h[4 * j + 0] * Cv.x + h[4 * j + 1] * Cv.y
               + h[4 * j + 2] * Cv.z + h[4 * j + 3] * Cv.w;
        }
        int tt = c * CLEN + t;
        int ot = rev ? (LL - 1 - tt) : tt;
        size_t oi = ((size_t)b * LL + ot) * DI + d;
        float val = y + uv * Dpv;
        if (rev) g[oi] += val;
        else     g[oi] = val;
    }
}

// ---------------- gate: gb = bf16(g * silu(z)) ------------------------------
__global__ __launch_bounds__(256)
void gate_kernel(const float* __restrict__ g, const float* __restrict__ xz,
                 unsigned short* __restrict__ gb)
{
    int gid = blockIdx.x * 256 + threadIdx.x;   // over B*L*DI
    int d = gid % DI;
    int bt = gid / DI;
    float z = xz[(size_t)bt * (2 * DI) + DI + d];
    gb[gid] = f2bf(g[gid] * siluf(z));
}

// ---------------------------------------------------------------------------
extern "C" void kernel_launch(void* const* d_in, const int* in_sizes, int n_in,
                              void* d_out, int out_size, void* d_ws, size_t ws_size,
                              hipStream_t stream)
{
    const float* h_r        = (const float*)d_in[0];
    const float* h_i        = (const float*)d_in[1];
    const float* ln_w       = (const float*)d_in[2];
    const float* ln_b       = (const float*)d_in[3];
    const float* in_w       = (const float*)d_in[4];
    const float* conv_w     = (const float*)d_in[5];
    const float* conv_bias  = (const float*)d_in[6];
    const float* xp_w       = (const float*)d_in[7];
    const float* dtp_w      = (const float*)d_in[8];
    const float* dtp_bias   = (const float*)d_in[9];
    const float* A_log      = (const float*)d_in[10];
    const float* D_p        = (const float*)d_in[11];
    const float* conv_w_b   = (const float*)d_in[12];
    const float* conv_bias_b= (const float*)d_in[13];
    const float* xp_w_b     = (const float*)d_in[14];
    const float* dtp_w_b    = (const float*)d_in[15];
    const float* dtp_bias_b = (const float*)d_in[16];
    const float* A_b_log    = (const float*)d_in[17];
    const float* D_b        = (const float*)d_in[18];
    const float* out_w      = (const float*)d_in[19];
    float* out = (float*)d_out;

    // workspace layout (floats)
    float*  ws   = (float*)d_ws;
    float*  g    = ws;                              // 6,291,456 f
    float*  xz   = g + (size_t)BB * LL * DI;        // 12,582,912 f
    float*  xc   = xz + (size_t)BB * LL * 2 * DI;   // 6,291,456 f
    float*  dtb  = xc + (size_t)BB * LL * DI;       // 6,291,456 f
    float*  xdbl = dtb + (size_t)BB * LL * DI;      // 327,680 f
    float*  Avm  = xdbl + (size_t)BB * LL * 80;     // 24,576 f
    float2* PQ   = (float2*)(Avm + DI * NS);        // CH*98304 f2 = 25.2 MB
    unsigned short* gb  = (unsigned short*)(PQ + (size_t)CH * BB * DI * NS);
    unsigned short* hnb = gb;          // alias: dead before gate writes gb
    float* xpart = (float*)gb;         // alias: live only conv->reduce (10.5MB)
    float* H0    = (float*)gb;         // alias: live only scan_mid->scan_p2
                                       //        (CH*98304 f = 12.58MB = gb size)
    unsigned short* wbi = gb + (size_t)BB * LL * DI;   // 2,359,296 us
    unsigned short* wbo = wbi + (size_t)2 * DI * DM;   // 1,179,648 us

    const size_t out_stride = (size_t)BB * LL * DM;

    for (int br = 0; br < 2; ++br) {
        const float* h = br ? h_i : h_r;

        ln_kernel<<<BB * LL, 256, 0, stream>>>(h, ln_w + br * DM, ln_b + br * DM, hnb);

        cast_kernel<<<(2 * DI * DM) / 1024, 256, 0, stream>>>(
            in_w + (size_t)br * 2 * DI * DM, wbi);
        cast_kernel<<<(DM * DI) / 1024, 256, 0, stream>>>(
            out_w + (size_t)br * DM * DI, wbo);

        // xz = hn @ in_w.T   [4096 x 3072], K=768  (bf16 MFMA)
        gemm_mfma_bt<<<dim3((2 * DI) / 128, (BB * LL) / 128), 256, 0, stream>>>(
            hnb, DM, wbi, DM, xz, 2 * DI, DM);

        for (int dir = 0; dir < 2; ++dir) {
            const float* cw = (dir ? conv_w_b : conv_w) + (size_t)br * DI * 4;
            const float* cb = (dir ? conv_bias_b : conv_bias) + (size_t)br * DI;
            const float* xw = (dir ? xp_w_b : xp_w) + (size_t)br * 80 * DI;
            const float* dw = (dir ? dtp_w_b : dtp_w) + (size_t)br * DI * RK;
            const float* db = (dir ? dtp_bias_b : dtp_bias) + (size_t)br * DI;
            const float* al = (dir ? A_b_log : A_log) + (size_t)br * DI * NS;
            const float* dp = (dir ? D_b : D_p) + (size_t)br * DI;

            conv_silu_kernel<<<(BB * LL * DI) / 256, 256, 0, stream>>>(xz, cw, cb, xc, dir);

            // xdbl = xc @ xp_w.T  [4096 x 80], K=1536 (fp32 split-K + reduce)
            xproj_partial<<<dim3(XKS, (BB * LL) / 64), 256, 0, stream>>>(xc, xw, xpart);
            xproj_reduce<<<(BB * LL * 80) / 256, 256, 0, stream>>>(xpart, xdbl);

            // dt = softplus(xdbl[:, :48] @ dtp_w.T + bias)  [4096 x 1536], K=48
            dtproj_kernel<<<dim3(DI / 128, (BB * LL) / 64), 256, 0, stream>>>(
                xdbl, dw, db, dtb);

            // chunked parallel scan
            aexp_kernel<<<(DI * NS) / 256, 256, 0, stream>>>(al, Avm);
            scan_p1<<<dim3(BB * DB6, CH), 256, 0, stream>>>(dtb, xc, xdbl, Avm, PQ);
            scan_mid<<<(BB * DI * NS) / 256, 256, 0, stream>>>(PQ, H0);
            scan_p2<<<dim3(BB * DB6, CH), 256, 0, stream>>>(
                dtb, xc, xdbl, Avm, dp, H0, g, dir);
        }

        gate_kernel<<<(BB * LL * DI) / 256, 256, 0, stream>>>(g, xz, gb);

        // out = g @ out_w.T   [4096 x 768], K=1536  (bf16 MFMA)
        gemm_mfma_bt<<<dim3(DM / 128, (BB * LL) / 128), 256, 0, stream>>>(
            gb, DI, wbo, DI, out + br * out_stride, DM, DI);
    }
}

// Round 7
// 966.800 us; speedup vs baseline: 1.3206x; 1.3206x over previous
//
#include <hip/hip_runtime.h>
#include <hip/hip_bf16.h>
#include <math.h>

// ---------------------------------------------------------------------------
// MambaBlock (bimamba v2). Round 6:
//  - dt_proj v2: 32x128 tile, thread = 4 rows x 4 consecutive cols, W staged
//    row-per-thread (conflict-free), k-loop unroll capped at 8.
//    R5's version hit VGPR=256 -> scratch spill (WRITE_SIZE 100MB) -> 119us.
//  - everything else unchanged from R4/R5.
// Shapes: B=4, L=1024, D_MODEL=768, D_INNER=1536, DT_RANK=48, D_STATE=16.
// ---------------------------------------------------------------------------

#define BB 4
#define LL 1024
#define DM 768
#define DI 1536
#define RK 48
#define NS 16
#define CH 32          // scan chunks
#define CLEN 32        // LL / CH
#define DB6 (DI / 256) // d-blocks per batch in scan
#define XKS 8          // x_proj split-K chunks
#define XKC 192        // 1536 / XKS

typedef __attribute__((ext_vector_type(8))) short bf16x8;
typedef __attribute__((ext_vector_type(4))) float f32x4;

__device__ __forceinline__ float siluf(float x) {
    return x / (1.f + __expf(-x));
}
__device__ __forceinline__ float softplusf(float x) {
    return (x > 20.f) ? x : log1pf(__expf(x));
}
__device__ __forceinline__ unsigned short f2bf(float x) {
    __hip_bfloat16 h = __float2bfloat16(x);
    return *(unsigned short*)&h;
}
__device__ __forceinline__ void async_cp16(const void* g, void* l) {
    __builtin_amdgcn_global_load_lds(
        (const __attribute__((address_space(1))) void*)g,
        (__attribute__((address_space(3))) void*)l, 16, 0, 0);
}

// ---------------- LayerNorm: one block per row of 768, bf16 out ------------
__global__ __launch_bounds__(256)
void ln_kernel(const float* __restrict__ h, const float* __restrict__ w,
               const float* __restrict__ bvec, unsigned short* __restrict__ out)
{
    int row = blockIdx.x;                 // 0 .. B*L-1
    const float* x = h + (size_t)row * DM;
    int tid = threadIdx.x;
    float v[3];
    float s = 0.f, s2 = 0.f;
#pragma unroll
    for (int j = 0; j < 3; ++j) {
        v[j] = x[tid + j * 256];
        s += v[j];
        s2 += v[j] * v[j];
    }
#pragma unroll
    for (int off = 32; off > 0; off >>= 1) {
        s += __shfl_down(s, off);
        s2 += __shfl_down(s2, off);
    }
    __shared__ float sw[4], sw2[4], stat[2];
    int wid = tid >> 6;
    if ((tid & 63) == 0) { sw[wid] = s; sw2[wid] = s2; }
    __syncthreads();
    if (tid == 0) {
        float a = sw[0] + sw[1] + sw[2] + sw[3];
        float a2 = sw2[0] + sw2[1] + sw2[2] + sw2[3];
        float mu = a * (1.f / DM);
        float var = a2 * (1.f / DM) - mu * mu;
        stat[0] = mu;
        stat[1] = rsqrtf(var + 1e-5f);
    }
    __syncthreads();
    float mu = stat[0], rs = stat[1];
    unsigned short* o = out + (size_t)row * DM;
#pragma unroll
    for (int j = 0; j < 3; ++j) {
        int i = tid + j * 256;
        o[i] = f2bf((v[j] - mu) * rs * w[i] + bvec[i]);
    }
}

// ---------------- fp32 -> bf16 cast (4 elems / thread) ---------------------
__global__ __launch_bounds__(256)
void cast_kernel(const float* __restrict__ x, unsigned short* __restrict__ y)
{
    int i = (blockIdx.x * 256 + threadIdx.x) * 4;
    float4 v = *(const float4*)(x + i);
    y[i + 0] = f2bf(v.x);
    y[i + 1] = f2bf(v.y);
    y[i + 2] = f2bf(v.z);
    y[i + 3] = f2bf(v.w);
}

// ---------------- Avm = -exp(A_log) ----------------------------------------
__global__ __launch_bounds__(256)
void aexp_kernel(const float* __restrict__ A_log, float* __restrict__ Avm)
{
    int i = blockIdx.x * 256 + threadIdx.x;     // over DI*NS
    Avm[i] = -expf(A_log[i]);
}

// ---------------- bf16 MFMA GEMM: C = A @ B^T (fp32 out) -------------------
// async global->LDS staging (16B/lane), 128x128 tile, BK=32.
__global__ __launch_bounds__(256)
void gemm_mfma_bt(const unsigned short* __restrict__ A, int lda,
                  const unsigned short* __restrict__ B, int ldb,
                  float* __restrict__ C, int ldc, int K)
{
    __shared__ unsigned short As[128 * 32];
    __shared__ unsigned short Bs[128 * 32];
    int tid = threadIdx.x;
    int wave = tid >> 6, lane = tid & 63;
    int wm = wave & 1, wn = wave >> 1;      // 2x2 wave grid
    int quad = lane >> 4, lr = lane & 15;
    int m0 = blockIdx.y * 128, n0 = blockIdx.x * 128;

    f32x4 acc[4][4];
#pragma unroll
    for (int i = 0; i < 4; ++i)
#pragma unroll
        for (int j = 0; j < 4; ++j) acc[i][j] = (f32x4){0.f, 0.f, 0.f, 0.f};

    for (int kt = 0; kt < K; kt += 32) {
        // stage 128x32 of A and B: LDS dest = wave-uniform base + lane*16
#pragma unroll
        for (int i = 0; i < 2; ++i) {
            int idx = tid + i * 256;               // 0..511
            int row = idx >> 2, col = (idx & 3) * 8;
            async_cp16(A + (size_t)(m0 + row) * lda + kt + col, &As[idx * 8]);
            async_cp16(B + (size_t)(n0 + row) * ldb + kt + col, &Bs[idx * 8]);
        }
        __syncthreads();

        bf16x8 af[4], bf[4];
#pragma unroll
        for (int mt = 0; mt < 4; ++mt)
            af[mt] = *(const bf16x8*)(&As[(wm * 64 + mt * 16 + lr) * 32 + quad * 8]);
#pragma unroll
        for (int nt = 0; nt < 4; ++nt)
            bf[nt] = *(const bf16x8*)(&Bs[(wn * 64 + nt * 16 + lr) * 32 + quad * 8]);
#pragma unroll
        for (int mt = 0; mt < 4; ++mt)
#pragma unroll
            for (int nt = 0; nt < 4; ++nt)
                acc[mt][nt] = __builtin_amdgcn_mfma_f32_16x16x32_bf16(
                    af[mt], bf[nt], acc[mt][nt], 0, 0, 0);
        __syncthreads();
    }

#pragma unroll
    for (int mt = 0; mt < 4; ++mt) {
#pragma unroll
        for (int nt = 0; nt < 4; ++nt) {
#pragma unroll
            for (int e = 0; e < 4; ++e) {
                int m = m0 + wm * 64 + mt * 16 + quad * 4 + e;
                int n = n0 + wn * 64 + nt * 16 + lr;
                C[(size_t)m * ldc + n] = acc[mt][nt][e];
            }
        }
    }
}

// ---------------- dt_proj: C = softplus(A[:, :48] @ W^T + bias) -------------
// A: xdbl [4096 x 80] (first 48 cols); W: [1536 x 48]; C: [4096 x 1536].
// 32x128 tile; thread = 4 rows x 4 consecutive cols; K=48, unroll 8.
__global__ __launch_bounds__(256)
void dtproj_kernel(const float* __restrict__ A, const float* __restrict__ W,
                   const float* __restrict__ bias, float* __restrict__ C)
{
    __shared__ float As[32][48];    // [m][k]; reads broadcast (2-way/wave)
    __shared__ float Ws[48][128];   // [k][n]; b128 reads conflict-free
    int tid = threadIdx.x;
    int m0 = blockIdx.y * 32, n0 = blockIdx.x * 128;

    // stage A: 32 rows x 48 cols = 384 float4
    for (int i = tid; i < 384; i += 256) {
        int r = i / 12, j = i % 12;
        *(float4*)(&As[r][j * 4]) =
            *(const float4*)(A + (size_t)(m0 + r) * 80 + j * 4);
    }
    // stage W: 128 threads, thread owns row n -> writes bank n%32 (2-way free)
    if (tid < 128) {
        const float* wr = W + (size_t)(n0 + tid) * RK;
#pragma unroll
        for (int j = 0; j < 12; ++j) {
            float4 v = *(const float4*)(wr + j * 4);
            Ws[j * 4 + 0][tid] = v.x;
            Ws[j * 4 + 1][tid] = v.y;
            Ws[j * 4 + 2][tid] = v.z;
            Ws[j * 4 + 3][tid] = v.w;
        }
    }
    __syncthreads();

    int tx = tid & 31, ty = tid >> 5;   // cols tx*4..tx*4+3, rows ty*4..ty*4+3
    float acc[4][4];
#pragma unroll
    for (int i = 0; i < 4; ++i)
#pragma unroll
        for (int j = 0; j < 4; ++j) acc[i][j] = 0.f;

#pragma unroll 8
    for (int k = 0; k < RK; ++k) {
        float4 w = *(const float4*)(&Ws[k][tx * 4]);
        float a0 = As[ty * 4 + 0][k];
        float a1 = As[ty * 4 + 1][k];
        float a2 = As[ty * 4 + 2][k];
        float a3 = As[ty * 4 + 3][k];
        acc[0][0] += a0 * w.x; acc[0][1] += a0 * w.y;
        acc[0][2] += a0 * w.z; acc[0][3] += a0 * w.w;
        acc[1][0] += a1 * w.x; acc[1][1] += a1 * w.y;
        acc[1][2] += a1 * w.z; acc[1][3] += a1 * w.w;
        acc[2][0] += a2 * w.x; acc[2][1] += a2 * w.y;
        acc[2][2] += a2 * w.z; acc[2][3] += a2 * w.w;
        acc[3][0] += a3 * w.x; acc[3][1] += a3 * w.y;
        acc[3][2] += a3 * w.z; acc[3][3] += a3 * w.w;
    }

    float4 bv = *(const float4*)(bias + n0 + tx * 4);
#pragma unroll
    for (int i = 0; i < 4; ++i) {
        float4 o;
        o.x = softplusf(acc[i][0] + bv.x);
        o.y = softplusf(acc[i][1] + bv.y);
        o.z = softplusf(acc[i][2] + bv.z);
        o.w = softplusf(acc[i][3] + bv.w);
        *(float4*)(C + (size_t)(m0 + ty * 4 + i) * DI + n0 + tx * 4) = o;
    }
}

// ---------------- x_proj split-K partial GEMM -------------------------------
__global__ __launch_bounds__(256)
void xproj_partial(const float* __restrict__ A, const float* __restrict__ W,
                   float* __restrict__ part)
{
    __shared__ float As[32][68];
    __shared__ float Ws[32][84];
    int tid = threadIdx.x;
    int tx = tid & 15, ty = tid >> 4;
    int k0 = blockIdx.x * XKC;
    int m0 = blockIdx.y * 64;

    float acc[4][5];
#pragma unroll
    for (int i = 0; i < 4; ++i)
#pragma unroll
        for (int j = 0; j < 5; ++j) acc[i][j] = 0.f;

    for (int kt = 0; kt < XKC; kt += 32) {
#pragma unroll
        for (int i = 0; i < 2; ++i) {
            int idx = tid + i * 256;
            int r = idx >> 3, c4 = (idx & 7) * 4;
            float4 v = *(const float4*)(A + (size_t)(m0 + r) * DI + k0 + kt + c4);
            As[c4 + 0][r] = v.x;
            As[c4 + 1][r] = v.y;
            As[c4 + 2][r] = v.z;
            As[c4 + 3][r] = v.w;
        }
        for (int idx = tid; idx < 640; idx += 256) {
            int r = idx >> 3, c4 = (idx & 7) * 4;
            float4 v = *(const float4*)(W + (size_t)r * DI + k0 + kt + c4);
            Ws[c4 + 0][r] = v.x;
            Ws[c4 + 1][r] = v.y;
            Ws[c4 + 2][r] = v.z;
            Ws[c4 + 3][r] = v.w;
        }
        __syncthreads();
#pragma unroll
        for (int kk = 0; kk < 32; ++kk) {
            float a[4], w[5];
#pragma unroll
            for (int i = 0; i < 4; ++i) a[i] = As[kk][ty * 4 + i];
#pragma unroll
            for (int j = 0; j < 5; ++j) w[j] = Ws[kk][tx + 16 * j];
#pragma unroll
            for (int i = 0; i < 4; ++i)
#pragma unroll
                for (int j = 0; j < 5; ++j) acc[i][j] += a[i] * w[j];
        }
        __syncthreads();
    }

    float* p = part + ((size_t)blockIdx.x * BB * LL + m0) * 80;
#pragma unroll
    for (int i = 0; i < 4; ++i)
#pragma unroll
        for (int j = 0; j < 5; ++j)
            p[(size_t)(ty * 4 + i) * 80 + tx + 16 * j] = acc[i][j];
}

// ---------------- x_proj reduce: xdbl = sum over XKS partials ---------------
__global__ __launch_bounds__(256)
void xproj_reduce(const float* __restrict__ part, float* __restrict__ xdbl)
{
    int i = blockIdx.x * 256 + threadIdx.x;     // over 4096*80
    float s = 0.f;
#pragma unroll
    for (int ks = 0; ks < XKS; ++ks)
        s += part[(size_t)ks * BB * LL * 80 + i];
    xdbl[i] = s;
}

// ---------------- causal depthwise conv (k=4) + silu ------------------------
__global__ __launch_bounds__(256)
void conv_silu_kernel(const float* __restrict__ xz, const float* __restrict__ w,
                      const float* __restrict__ bias, float* __restrict__ xc,
                      int rev)
{
    int gid = blockIdx.x * 256 + threadIdx.x;   // over B*L*DI
    int d = gid % DI;
    int bt = gid / DI;
    int t = bt % LL;
    int b = bt / LL;
    float acc = bias[d];
#pragma unroll
    for (int i = 0; i < 4; ++i) {
        int tt = t - 3 + i;
        if (tt >= 0) {
            int st = rev ? (LL - 1 - tt) : tt;
            acc += xz[((size_t)(b * LL + st)) * (2 * DI) + d] * w[d * 4 + i];
        }
    }
    xc[gid] = siluf(acc);
}

// ---------------- selective scan, pass 1: per-chunk (p, q) ------------------
__global__ __launch_bounds__(256)
void scan_p1(const float* __restrict__ dt, const float* __restrict__ u,
             const float* __restrict__ xdbl, const float* __restrict__ Avm,
             float2* __restrict__ PQ)
{
    int c = blockIdx.y;
    int b = blockIdx.x / DB6;
    int d = (blockIdx.x % DB6) * 256 + threadIdx.x;

    float Av[16];
    {
        const float4* a4 = (const float4*)(Avm + (size_t)d * NS);
#pragma unroll
        for (int j = 0; j < 4; ++j) {
            float4 v = a4[j];
            Av[4 * j + 0] = v.x; Av[4 * j + 1] = v.y;
            Av[4 * j + 2] = v.z; Av[4 * j + 3] = v.w;
        }
    }

    __shared__ float Bs[CLEN * NS];
    for (int i = threadIdx.x; i < CLEN * NS; i += 256) {
        int t = i >> 4, n = i & 15;
        Bs[i] = xdbl[((size_t)(b * LL + c * CLEN + t)) * 80 + 48 + n];
    }
    __syncthreads();

    float q[16];
#pragma unroll
    for (int n = 0; n < 16; ++n) q[n] = 0.f;
    float dtsum = 0.f;

    size_t base = ((size_t)b * LL + c * CLEN) * DI + d;
    float dtr[8], ur[8];
#pragma unroll
    for (int i = 0; i < 8; ++i) {
        dtr[i] = dt[base + (size_t)i * DI];
        ur[i]  = u[base + (size_t)i * DI];
    }
#pragma unroll
    for (int t = 0; t < CLEN; ++t) {
        float dtv = dtr[t & 7], uv = ur[t & 7];
        if (t + 8 < CLEN) {
            dtr[t & 7] = dt[base + (size_t)(t + 8) * DI];
            ur[t & 7]  = u[base + (size_t)(t + 8) * DI];
        }
        float du = dtv * uv;
        dtsum += dtv;
        const float4* b4 = (const float4*)(Bs + t * NS);
#pragma unroll
        for (int j = 0; j < 4; ++j) {
            float4 Bv = b4[j];
            q[4 * j + 0] = __expf(dtv * Av[4 * j + 0]) * q[4 * j + 0] + du * Bv.x;
            q[4 * j + 1] = __expf(dtv * Av[4 * j + 1]) * q[4 * j + 1] + du * Bv.y;
            q[4 * j + 2] = __expf(dtv * Av[4 * j + 2]) * q[4 * j + 2] + du * Bv.z;
            q[4 * j + 3] = __expf(dtv * Av[4 * j + 3]) * q[4 * j + 3] + du * Bv.w;
        }
    }

    float2* o = PQ + (size_t)c * (BB * DI * NS) + (size_t)(b * DI + d) * NS;
#pragma unroll
    for (int n = 0; n < 16; ++n)
        o[n] = make_float2(__expf(dtsum * Av[n]), q[n]);
}

// ---------------- scan mid: compose chunk prefixes -> H0 --------------------
__global__ __launch_bounds__(256)
void scan_mid(const float2* __restrict__ PQ, float* __restrict__ H0)
{
    int gid = blockIdx.x * 256 + threadIdx.x;   // over BB*DI*NS
    float h = 0.f;
#pragma unroll
    for (int c = 0; c < CH; ++c) {
        H0[(size_t)c * (BB * DI * NS) + gid] = h;
        float2 s = PQ[(size_t)c * (BB * DI * NS) + gid];
        h = s.x * h + s.y;
    }
}

// ---------------- selective scan, pass 2: replay with true h0 ---------------
__global__ __launch_bounds__(256)
void scan_p2(const float* __restrict__ dt, const float* __restrict__ u,
             const float* __restrict__ xdbl, const float* __restrict__ Avm,
             const float* __restrict__ Dp, const float* __restrict__ H0,
             float* __restrict__ g, int rev)
{
    int c = blockIdx.y;
    int b = blockIdx.x / DB6;
    int d = (blockIdx.x % DB6) * 256 + threadIdx.x;

    float Av[16];
    {
        const float4* a4 = (const float4*)(Avm + (size_t)d * NS);
#pragma unroll
        for (int j = 0; j < 4; ++j) {
            float4 v = a4[j];
            Av[4 * j + 0] = v.x; Av[4 * j + 1] = v.y;
            Av[4 * j + 2] = v.z; Av[4 * j + 3] = v.w;
        }
    }
    float h[16];
    {
        const float4* h4 = (const float4*)(H0 + (size_t)c * (BB * DI * NS)
                                           + (size_t)(b * DI + d) * NS);
#pragma unroll
        for (int j = 0; j < 4; ++j) {
            float4 v = h4[j];
            h[4 * j + 0] = v.x; h[4 * j + 1] = v.y;
            h[4 * j + 2] = v.z; h[4 * j + 3] = v.w;
        }
    }
    float Dpv = Dp[d];

    __shared__ float Bs[CLEN * NS];
    __shared__ float Cs[CLEN * NS];
    for (int i = threadIdx.x; i < CLEN * NS; i += 256) {
        int t = i >> 4, n = i & 15;
        size_t src = ((size_t)(b * LL + c * CLEN + t)) * 80;
        Bs[i] = xdbl[src + 48 + n];
        Cs[i] = xdbl[src + 64 + n];
    }
    __syncthreads();

    size_t base = ((size_t)b * LL + c * CLEN) * DI + d;
    float dtr[8], ur[8];
#pragma unroll
    for (int i = 0; i < 8; ++i) {
        dtr[i] = dt[base + (size_t)i * DI];
        ur[i]  = u[base + (size_t)i * DI];
    }
#pragma unroll
    for (int t = 0; t < CLEN; ++t) {
        float dtv = dtr[t & 7], uv = ur[t & 7];
        if (t + 8 < CLEN) {
            dtr[t & 7] = dt[base + (size_t)(t + 8) * DI];
            ur[t & 7]  = u[base + (size_t)(t + 8) * DI];
        }
        float du = dtv * uv;
        float y = 0.f;
        const float4* b4 = (const float4*)(Bs + t * NS);
        const float4* c4 = (const float4*)(Cs + t * NS);
#pragma unroll
        for (int j = 0; j < 4; ++j) {
            float4 Bv = b4[j];
            float4 Cv = c4[j];
            h[4 * j + 0] = __expf(dtv * Av[4 * j + 0]) * h[4 * j + 0] + du * Bv.x;
            h[4 * j + 1] = __expf(dtv * Av[4 * j + 1]) * h[4 * j + 1] + du * Bv.y;
            h[4 * j + 2] = __expf(dtv * Av[4 * j + 2]) * h[4 * j + 2] + du * Bv.z;
            h[4 * j + 3] = __expf(dtv * Av[4 * j + 3]) * h[4 * j + 3] + du * Bv.w;
            y += h[4 * j + 0] * Cv.x + h[4 * j + 1] * Cv.y
               + h[4 * j + 2] * Cv.z + h[4 * j + 3] * Cv.w;
        }
        int tt = c * CLEN + t;
        int ot = rev ? (LL - 1 - tt) : tt;
        size_t oi = ((size_t)b * LL + ot) * DI + d;
        float val = y + uv * Dpv;
        if (rev) g[oi] += val;
        else     g[oi] = val;
    }
}

// ---------------- gate: gb = bf16(g * silu(z)) ------------------------------
__global__ __launch_bounds__(256)
void gate_kernel(const float* __restrict__ g, const float* __restrict__ xz,
                 unsigned short* __restrict__ gb)
{
    int gid = blockIdx.x * 256 + threadIdx.x;   // over B*L*DI
    int d = gid % DI;
    int bt = gid / DI;
    float z = xz[(size_t)bt * (2 * DI) + DI + d];
    gb[gid] = f2bf(g[gid] * siluf(z));
}

// ---------------------------------------------------------------------------
extern "C" void kernel_launch(void* const* d_in, const int* in_sizes, int n_in,
                              void* d_out, int out_size, void* d_ws, size_t ws_size,
                              hipStream_t stream)
{
    const float* h_r        = (const float*)d_in[0];
    const float* h_i        = (const float*)d_in[1];
    const float* ln_w       = (const float*)d_in[2];
    const float* ln_b       = (const float*)d_in[3];
    const float* in_w       = (const float*)d_in[4];
    const float* conv_w     = (const float*)d_in[5];
    const float* conv_bias  = (const float*)d_in[6];
    const float* xp_w       = (const float*)d_in[7];
    const float* dtp_w      = (const float*)d_in[8];
    const float* dtp_bias   = (const float*)d_in[9];
    const float* A_log      = (const float*)d_in[10];
    const float* D_p        = (const float*)d_in[11];
    const float* conv_w_b   = (const float*)d_in[12];
    const float* conv_bias_b= (const float*)d_in[13];
    const float* xp_w_b     = (const float*)d_in[14];
    const float* dtp_w_b    = (const float*)d_in[15];
    const float* dtp_bias_b = (const float*)d_in[16];
    const float* A_b_log    = (const float*)d_in[17];
    const float* D_b        = (const float*)d_in[18];
    const float* out_w      = (const float*)d_in[19];
    float* out = (float*)d_out;

    // workspace layout (floats)
    float*  ws   = (float*)d_ws;
    float*  g    = ws;                              // 6,291,456 f
    float*  xz   = g + (size_t)BB * LL * DI;        // 12,582,912 f
    float*  xc   = xz + (size_t)BB * LL * 2 * DI;   // 6,291,456 f
    float*  dtb  = xc + (size_t)BB * LL * DI;       // 6,291,456 f
    float*  xdbl = dtb + (size_t)BB * LL * DI;      // 327,680 f
    float*  Avm  = xdbl + (size_t)BB * LL * 80;     // 24,576 f
    float2* PQ   = (float2*)(Avm + DI * NS);        // CH*98304 f2 = 25.2 MB
    unsigned short* gb  = (unsigned short*)(PQ + (size_t)CH * BB * DI * NS);
    unsigned short* hnb = gb;          // alias: dead before gate writes gb
    float* xpart = (float*)gb;         // alias: live only conv->reduce (10.5MB)
    float* H0    = (float*)gb;         // alias: live only scan_mid->scan_p2
                                       //        (CH*98304 f = 12.58MB = gb size)
    unsigned short* wbi = gb + (size_t)BB * LL * DI;   // 2,359,296 us
    unsigned short* wbo = wbi + (size_t)2 * DI * DM;   // 1,179,648 us

    const size_t out_stride = (size_t)BB * LL * DM;

    for (int br = 0; br < 2; ++br) {
        const float* h = br ? h_i : h_r;

        ln_kernel<<<BB * LL, 256, 0, stream>>>(h, ln_w + br * DM, ln_b + br * DM, hnb);

        cast_kernel<<<(2 * DI * DM) / 1024, 256, 0, stream>>>(
            in_w + (size_t)br * 2 * DI * DM, wbi);
        cast_kernel<<<(DM * DI) / 1024, 256, 0, stream>>>(
            out_w + (size_t)br * DM * DI, wbo);

        // xz = hn @ in_w.T   [4096 x 3072], K=768  (bf16 MFMA)
        gemm_mfma_bt<<<dim3((2 * DI) / 128, (BB * LL) / 128), 256, 0, stream>>>(
            hnb, DM, wbi, DM, xz, 2 * DI, DM);

        for (int dir = 0; dir < 2; ++dir) {
            const float* cw = (dir ? conv_w_b : conv_w) + (size_t)br * DI * 4;
            const float* cb = (dir ? conv_bias_b : conv_bias) + (size_t)br * DI;
            const float* xw = (dir ? xp_w_b : xp_w) + (size_t)br * 80 * DI;
            const float* dw = (dir ? dtp_w_b : dtp_w) + (size_t)br * DI * RK;
            const float* db = (dir ? dtp_bias_b : dtp_bias) + (size_t)br * DI;
            const float* al = (dir ? A_b_log : A_log) + (size_t)br * DI * NS;
            const float* dp = (dir ? D_b : D_p) + (size_t)br * DI;

            conv_silu_kernel<<<(BB * LL * DI) / 256, 256, 0, stream>>>(xz, cw, cb, xc, dir);

            // xdbl = xc @ xp_w.T  [4096 x 80], K=1536 (fp32 split-K + reduce)
            xproj_partial<<<dim3(XKS, (BB * LL) / 64), 256, 0, stream>>>(xc, xw, xpart);
            xproj_reduce<<<(BB * LL * 80) / 256, 256, 0, stream>>>(xpart, xdbl);

            // dt = softplus(xdbl[:, :48] @ dtp_w.T + bias)  [4096 x 1536], K=48
            dtproj_kernel<<<dim3(DI / 128, (BB * LL) / 32), 256, 0, stream>>>(
                xdbl, dw, db, dtb);

            // chunked parallel scan
            aexp_kernel<<<(DI * NS) / 256, 256, 0, stream>>>(al, Avm);
            scan_p1<<<dim3(BB * DB6, CH), 256, 0, stream>>>(dtb, xc, xdbl, Avm, PQ);
            scan_mid<<<(BB * DI * NS) / 256, 256, 0, stream>>>(PQ, H0);
            scan_p2<<<dim3(BB * DB6, CH), 256, 0, stream>>>(
                dtb, xc, xdbl, Avm, dp, H0, g, dir);
        }

        gate_kernel<<<(BB * LL * DI) / 256, 256, 0, stream>>>(g, xz, gb);

        // out = g @ out_w.T   [4096 x 768], K=1536  (bf16 MFMA)
        gemm_mfma_bt<<<dim3(DM / 128, (BB * LL) / 128), 256, 0, stream>>>(
            gb, DI, wbo, DI, out + br * out_stride, DM, DI);
    }
}